// Round 11
// baseline (254.152 us; speedup 1.0000x reference)
//
#include <hip/hip_runtime.h>

#define B_ 8
#define T_ 1024
#define CG_ 256
#define CAP2 26
#define SENT_E 0xFC01u          // ver=31 (never matches), j=1025

// ---------------- pack: x (8,1024,1024) f32 -> tok rows (B*Cg, T) u8 ----------------
__global__ __launch_bounds__(256) void pack_kernel(const float* __restrict__ x,
                                                   unsigned char* __restrict__ tok){
  __shared__ unsigned char tl[256][80];
  const int b  = blockIdx.x >> 4;
  const int t0 = (blockIdx.x & 15) << 6;
  const int g  = threadIdx.x;
  const float* xb = x + ((size_t)(b*T_ + t0) * 1024) + g*4;
  for (int tt = 0; tt < 64; tt++){
    const float4 v = *reinterpret_cast<const float4*>(xb + (size_t)tt*1024);
    unsigned int t = (v.x>0.f?1u:0u) | (v.y>0.f?2u:0u) | (v.z>0.f?4u:0u) | (v.w>0.f?8u:0u);
    tl[g][tt] = (unsigned char)t;
  }
  __syncthreads();
  const int gg  = threadIdx.x >> 2;
  const int off = (threadIdx.x & 3) * 16;
  for (int it = 0; it < 4; it++){
    const int g2 = gg + it*64;
    const uint4 w = *reinterpret_cast<const uint4*>(&tl[g2][off]);
    *reinterpret_cast<uint4*>(tok + (size_t)(b*CG_ + g2)*T_ + t0 + off) = w;
  }
}

// Trigram-sparse ROSA DP with SORTED buckets (ballot-rank build, no reliance on
// atomic lane order). Per step:
//   run-1 key: lastpos1 register (lane v holds last j with x[j]==v)   [scalar]
//   run-2 key: buckets sorted by j; valid lanes (jl<i) are a prefix ->
//              m=popcount(ballot), key = 2048 + readlane(jl, m-1)     [scalar]
//   run>=3 (22% of steps, precomputed bitmap): trig lanes gather/write val[],
//              small DPP reduce. stale -> rn=3, fresh -> rn=run+1 (exact).
struct alignas(16) RowLds {
  unsigned int   val[1092];     // cells 0..1023, [1024] dummy-read, [1025..1088] trash
                                // build alias: val[0..255]=tmp base, val[256..767]=cnt3 nibbles
  unsigned char  t[1040];       // tokens + pad
  unsigned short bg[256*CAP2];  // buckets: (ver<<11)|j, sorted by j, sentinel SENT_E
  unsigned int   cnt2[256];
};                              // 19744 B/wave, x4 = 78976 B -> 2 blocks/CU

__global__ __launch_bounds__(256, 2) void rosa_tri3_kernel(const unsigned char* __restrict__ tok,
                                                           unsigned char* __restrict__ pred){
  __shared__ RowLds S[4];
  const int wave = threadIdx.x >> 6;
  const unsigned int lane = threadIdx.x & 63u;
  const int row = blockIdx.x * 4 + wave;
  RowLds& R = S[wave];

  // stage tokens + pad
  { const uint4 v = *reinterpret_cast<const uint4*>(tok + (size_t)row*T_ + lane*16);
    *reinterpret_cast<uint4*>(&R.t[lane*16]) = v;
    if (lane == 0u) *reinterpret_cast<uint4*>(&R.t[1024]) = make_uint4(0,0,0,0); }
  // zero cnt2 + cnt3 region (val[256..768))
  *reinterpret_cast<uint4*>(&R.cnt2[lane*4]) = make_uint4(0,0,0,0);
  { uint4* p = reinterpret_cast<uint4*>(R.val);
    p[64 + lane] = make_uint4(0,0,0,0); p[128 + lane] = make_uint4(0,0,0,0); }
  // fill bg with sentinel
  { const unsigned int s2 = SENT_E | (SENT_E << 16);
    const uint4 s4 = make_uint4(s2,s2,s2,s2);
    uint4* p = reinterpret_cast<uint4*>(R.bg);
    #pragma unroll
    for (int m = 0; m < 13; m++) p[m*64 + lane] = s4; }

  const unsigned long long below = (1ull << lane) - 1ull;
  // build sorted buckets via ballot-rank (deterministic within/across chunks)
  #pragma unroll 1
  for (int k = 0; k < 16; k++){
    const unsigned int j = (unsigned)k*64u + lane;
    const unsigned int tj   = R.t[j];
    const unsigned int tjm1 = (j >= 1u) ? (unsigned)R.t[j-1] : 0u;
    const unsigned int v2 = (j >= 1u) ? ((tjm1 << 4) | tj) : 0x1FFu;
    unsigned long long mm = ~0ull;
    #pragma unroll
    for (int b = 0; b < 9; b++){
      const unsigned long long bb = __ballot(((v2 >> b) & 1u) != 0u);
      mm &= ((v2 >> b) & 1u) ? bb : ~bb;
    }
    const unsigned int rank  = (unsigned int)__popcll(mm & below);
    const unsigned int gsize = (unsigned int)__popcll(mm);
    if (rank == 0u && v2 < 256u){
      const unsigned int base = atomicAdd(&R.cnt2[v2], gsize);
      R.val[v2] = base;                       // tmp publish (program-order DS)
    }
    if (v2 < 256u){
      const unsigned int basep = R.val[v2];
      const unsigned int slot = basep + rank;
      if (slot < (unsigned)CAP2){
        const unsigned int ver = (j >= 2u) ? (unsigned)R.t[j-2] : 31u;
        R.bg[v2*CAP2 + slot] = (unsigned short)((ver << 11) | j);
      }
    }
    if (j >= 2u){
      const unsigned int tr = (((unsigned)R.t[j-2]) << 8) | (tjm1 << 4) | tj;
      atomicAdd(&R.val[256u + (tr >> 3)], 1u << ((tr & 7u) * 4u));
    }
  }
  // trigram-presence bitmap -> 2 VGPRs (lane c holds chunk c's lo/hi words)
  unsigned int vblo = 0u, vbhi = 0u;
  #pragma unroll 1
  for (int c = 0; c < 16; c++){
    const unsigned int ii = (unsigned)c*64u + lane;
    bool ta = false;
    if (ii >= 2u){
      const unsigned int tr = (((unsigned)R.t[ii-2]) << 8) | (((unsigned)R.t[ii-1]) << 4) | (unsigned)R.t[ii];
      ta = (((R.val[256u + (tr >> 3)] >> ((tr & 7u) * 4u)) & 15u) >= 2u);
    }
    const unsigned long long bm = __ballot(ta ? 1 : 0);
    vblo = (lane == (unsigned)c) ? (unsigned int)bm : vblo;
    vbhi = (lane == (unsigned)c) ? (unsigned int)(bm >> 32) : vbhi;
  }
  // init val stamps to 0xFFFF (overwrites tmp/cnt3 aliases)
  { const uint4 z = make_uint4(0xFFFF0000u,0xFFFF0000u,0xFFFF0000u,0xFFFF0000u);
    uint4* p = reinterpret_cast<uint4*>(R.val);
    #pragma unroll
    for (int m = 0; m < 4; m++) p[m*64 + lane] = z;
    if (lane < 17u) p[256 + lane] = z; }      // words 1024..1091

  // tokens -> registers
  unsigned int vtokk[16];
  #pragma unroll
  for (int k = 0; k < 16; k++) vtokk[k] = R.t[k*64 + lane];

  unsigned int lp1 = 0xFFFFFFFFu;             // lane v: last j with x[j]==v (-1 none)
  unsigned int ans = 0u;
  const bool lane26 = (lane < (unsigned)CAP2);

  int s_xi  = __builtin_amdgcn_readlane((int)vtokk[0], 0);
  int s_xp1 = __builtin_amdgcn_readlane((int)vtokk[0], 1);
  int s_xm1 = 0;
  unsigned int s_xm2v = 30u;                  // x[i-2]; 30 = never-match (i<2)
  unsigned int enA, enB;
  { const unsigned int b0 = (((unsigned)s_xm1 << 4) | (unsigned)s_xi);
    const unsigned int b1 = (((unsigned)s_xi  << 4) | (unsigned)s_xp1);
    enA = (unsigned int)R.bg[b0*CAP2 + lane];
    enB = (unsigned int)R.bg[b1*CAP2 + lane]; }

#define RSTEP(I0, DI, NEXTTOK_EXPR) do {                                          \
    const int i_ = (I0)*64 + (DI);                                                \
    const unsigned int en  = lane26 ? enA : SENT_E;                               \
    const unsigned int jl  = en & 0x7FFu;                                         \
    const int s_xp2 = (NEXTTOK_EXPR);                                             \
    const unsigned int s_bn = (((unsigned)s_xp1 << 4) | (unsigned)s_xp2);         \
    const unsigned int enN = (unsigned int)R.bg[s_bn*CAP2 + lane];                \
    /* run-1 scalar key */                                                        \
    const int s_lp1 = __builtin_amdgcn_readlane((int)lp1, s_xi);                  \
    unsigned int s_key = (s_lp1 < 0) ? 0u : (1024u + (unsigned)s_lp1);            \
    lp1 = (lane == (unsigned)s_xi) ? (unsigned)i_ : lp1;                          \
    /* run-2 scalar key: sorted prefix -> popcount + readlane */                  \
    const unsigned long long vm = __ballot(jl < (unsigned)i_);                    \
    const unsigned int m_ = (unsigned int)__popcll(vm);                           \
    const unsigned int idx = m_ ? (m_ - 1u) : 0u;                                 \
    const unsigned int j2 = (unsigned)__builtin_amdgcn_readlane((int)jl, (int)idx); \
    const unsigned int k2 = m_ ? (2048u + j2) : 0u;                               \
    s_key = k2 > s_key ? k2 : s_key;                                              \
    /* rare trig block (precomputed bit) */                                       \
    if ((unsigned int)s_sw & 1u){                                                 \
      const unsigned int ver = en >> 11;                                          \
      const bool trig = (ver == s_xm2v);                                          \
      const unsigned int g = R.val[jl - 1u];                                      \
      const unsigned int d = g - (((unsigned)(i_ - 1)) << 16);                    \
      const unsigned int rn = (d <= 1024u) ? (d + 1u) : 3u;                       \
      const unsigned int widx = trig ? jl : (1025u + lane);                       \
      R.val[widx] = (((unsigned)i_) << 16) | rn;                                  \
      unsigned int k3 = (rn << 10) | jl;                                          \
      k3 = (trig && jl < (unsigned)i_) ? k3 : 0u;                                 \
      int bb = (int)k3, tt;                                                       \
      tt = __builtin_amdgcn_mov_dpp(bb, 0x111, 0xf, 0xf, true); bb = ((unsigned)tt > (unsigned)bb) ? tt : bb; \
      tt = __builtin_amdgcn_mov_dpp(bb, 0x112, 0xf, 0xf, true); bb = ((unsigned)tt > (unsigned)bb) ? tt : bb; \
      tt = __builtin_amdgcn_mov_dpp(bb, 0x114, 0xf, 0xf, true); bb = ((unsigned)tt > (unsigned)bb) ? tt : bb; \
      tt = __builtin_amdgcn_mov_dpp(bb, 0x118, 0xf, 0xf, true); bb = ((unsigned)tt > (unsigned)bb) ? tt : bb; \
      const unsigned int r15 = (unsigned)__builtin_amdgcn_readlane(bb, 15);       \
      const unsigned int r31 = (unsigned)__builtin_amdgcn_readlane(bb, 31);       \
      const unsigned int rmx = r15 > r31 ? r15 : r31;                             \
      s_key = rmx > s_key ? rmx : s_key;                                          \
    }                                                                             \
    s_sw >>= 1;                                                                   \
    ans = (lane == (unsigned)(DI)) ? s_key : ans;                                 \
    s_xm2v = (i_ >= 1) ? (unsigned)s_xm1 : 30u;                                   \
    s_xm1 = s_xi; s_xi = s_xp1; s_xp1 = s_xp2;                                    \
    enA = enB; enB = enN;                                                         \
  } while(0)

  #pragma unroll
  for (int i0 = 0; i0 < 16; i0++){
    const unsigned int s_blo = (unsigned)__builtin_amdgcn_readlane((int)vblo, i0);
    const unsigned int s_bhi = (unsigned)__builtin_amdgcn_readlane((int)vbhi, i0);
    unsigned long long s_sw = ((unsigned long long)s_bhi << 32) | (unsigned long long)s_blo;
    #pragma unroll 1
    for (int di = 0; di < 62; di++){
      RSTEP(i0, di, __builtin_amdgcn_readlane((int)vtokk[i0], di + 2));
    }
    RSTEP(i0, 62, __builtin_amdgcn_readlane((int)vtokk[(i0+1) & 15], (i0 < 15) ? 0 : 62));
    RSTEP(i0, 63, __builtin_amdgcn_readlane((int)vtokk[(i0+1) & 15], (i0 < 15) ? 1 : 63));
    // epilogue: lane s finalizes step i0*64+s
    const unsigned int ab = ans;
    unsigned int pidx = (ab & 1023u) + 1u;
    pidx = pidx > 1023u ? 1023u : pidx;
    const unsigned int pt = R.t[pidx];
    pred[(size_t)row*T_ + i0*64 + lane] = (unsigned char)((ab >= 1024u) ? pt : 0u);
    ans = 0u;
  }
#undef RSTEP
}

// ---------------- expand: pred (B*Cg, T) u8 -> out (B,T,C) f32 ----------------
__global__ __launch_bounds__(256) void expand_kernel(const unsigned char* __restrict__ pred,
                                                     const float* __restrict__ emb0,
                                                     const float* __restrict__ emb1,
                                                     float* __restrict__ out){
  __shared__ unsigned char pl[64][80];
  const int bid = blockIdx.x;
  const int g0 = (bid & 3) << 6;
  const int t0 = ((bid >> 2) & 15) << 6;
  const int b  = bid >> 6;
  const int k  = threadIdx.x;
  {
    const int gg = k >> 2, off = (k & 3) * 16;
    const uint4 v = *reinterpret_cast<const uint4*>(pred + (size_t)(b*CG_ + g0 + gg)*T_ + t0 + off);
    *reinterpret_cast<uint4*>(&pl[gg][off]) = v;
  }
  __syncthreads();
  const int gg = k & 63;
  const int w  = k >> 6;
  const float4 e0 = *reinterpret_cast<const float4*>(emb0 + (g0+gg)*4);
  const float4 e1 = *reinterpret_cast<const float4*>(emb1 + (g0+gg)*4);
  for (int it = 0; it < 16; it++){
    const int tt = it*4 + w;
    const unsigned int pb = pl[gg][tt];
    float4 o;
    o.x = (pb & 1u) ? e1.x : e0.x;
    o.y = (pb & 2u) ? e1.y : e0.y;
    o.z = (pb & 4u) ? e1.z : e0.z;
    o.w = (pb & 8u) ? e1.w : e0.w;
    *reinterpret_cast<float4*>(out + (size_t)(b*T_ + t0 + tt)*1024 + (g0+gg)*4) = o;
  }
}

extern "C" void kernel_launch(void* const* d_in, const int* in_sizes, int n_in,
                              void* d_out, int out_size, void* d_ws, size_t ws_size,
                              hipStream_t stream){
  const float* x    = (const float*)d_in[0];
  const float* emb0 = (const float*)d_in[1];
  const float* emb1 = (const float*)d_in[2];
  float* out = (float*)d_out;
  unsigned char* tok  = (unsigned char*)d_ws;
  unsigned char* pred = tok + (size_t)B_*CG_*T_;
  pack_kernel<<<128, 256, 0, stream>>>(x, tok);
  rosa_tri3_kernel<<<(B_*CG_)/4, 256, 0, stream>>>(tok, pred);
  expand_kernel<<<512, 256, 0, stream>>>(pred, emb0, emb1, out);
}

// Round 12
// 210.710 us; speedup vs baseline: 1.2062x; 1.2062x over previous
//
#include <hip/hip_runtime.h>

#define B_ 8
#define T_ 1024
#define CG_ 256
#define CAP2 24
#define SENT_J 1025u

// ---------------- pack: x (8,1024,1024) f32 -> tok rows (B*Cg, T) u8 ----------------
__global__ __launch_bounds__(256) void pack_kernel(const float* __restrict__ x,
                                                   unsigned char* __restrict__ tok){
  __shared__ unsigned char tl[256][80];
  const int b  = blockIdx.x >> 4;
  const int t0 = (blockIdx.x & 15) << 6;
  const int g  = threadIdx.x;
  const float* xb = x + ((size_t)(b*T_ + t0) * 1024) + g*4;
  for (int tt = 0; tt < 64; tt++){
    const float4 v = *reinterpret_cast<const float4*>(xb + (size_t)tt*1024);
    unsigned int t = (v.x>0.f?1u:0u) | (v.y>0.f?2u:0u) | (v.z>0.f?4u:0u) | (v.w>0.f?8u:0u);
    tl[g][tt] = (unsigned char)t;
  }
  __syncthreads();
  const int gg  = threadIdx.x >> 2;
  const int off = (threadIdx.x & 3) * 16;
  for (int it = 0; it < 4; it++){
    const int g2 = gg + it*64;
    const uint4 w = *reinterpret_cast<const uint4*>(&tl[g2][off]);
    *reinterpret_cast<uint4*>(tok + (size_t)(b*CG_ + g2)*T_ + t0 + off) = w;
  }
}

// Bigram-sparse ROSA DP (R8 semantics, trimmed machinery).
//   bucket(v2) = sorted-or-not list of j with (x[j-1],x[j])=v2 (order irrelevant).
//   step i: lanes hold bucket(bigram(i)) entries; gather val[j-1]:
//     fresh (stamp i-1) -> rn = run+1 ; stale -> rn = 2 (prev run was exactly 1).
//   run-1 argmax via lastpos1 register (lane v holds last j with x[j]==v).
//   Per-step argmax deferred: 3-DPP 8-group maxes -> M8[di][0..2] (lanes 7/15/23),
//   run-1 key -> M8[di][3] (lane 62); full reduce once per 64-step block.
struct alignas(16) RowLds {
  unsigned int   val[1092];     // cells 0..1023, [1024] dummy-read, [1025..1088] trash
                                // build alias: val[0..255] = bucket counters
  unsigned char  t[1040];       // tokens + pad
  unsigned short bg[256*CAP2];  // buckets: plain j, sentinel 1025       (12288 B)
  unsigned int   M8[320];       // [64][5]: cols 0..2 group maxes, col 3 run-1 key
  unsigned int   trash[64];
};                              // 19232 B/wave, x4 = 76928 B -> 2 blocks/CU

__global__ __launch_bounds__(256, 2) void rosa_bg2_kernel(const unsigned char* __restrict__ tok,
                                                          unsigned char* __restrict__ pred){
  __shared__ RowLds S[4];
  const int wave = threadIdx.x >> 6;
  const unsigned int lane = threadIdx.x & 63u;
  const int row = blockIdx.x * 4 + wave;
  RowLds& R = S[wave];

  // stage tokens + pad
  { const uint4 v = *reinterpret_cast<const uint4*>(tok + (size_t)row*T_ + lane*16);
    *reinterpret_cast<uint4*>(&R.t[lane*16]) = v;
    if (lane == 0u) *reinterpret_cast<uint4*>(&R.t[1024]) = make_uint4(0,0,0,0); }
  // zero bucket counters (aliased over val[0..255])
  { uint4* p = reinterpret_cast<uint4*>(R.val);
    p[lane] = make_uint4(0,0,0,0); }
  // fill bg with sentinel
  { const unsigned int s2 = SENT_J | (SENT_J << 16);
    const uint4 s4 = make_uint4(s2,s2,s2,s2);
    uint4* p = reinterpret_cast<uint4*>(R.bg);
    #pragma unroll
    for (int m = 0; m < 12; m++) p[m*64 + lane] = s4; }   // 12*64*16 B = 12288 B
  // build buckets (order within bucket irrelevant; same-wave DS ordering)
  #pragma unroll
  for (int k = 0; k < 16; k++){
    const unsigned int j = (unsigned)k*64u + lane;
    if (j >= 1u){
      const unsigned int v2 = ((unsigned)R.t[j-1] << 4) | (unsigned)R.t[j];
      const unsigned int r = atomicAdd(&R.val[v2], 1u);
      if (r < (unsigned)CAP2) R.bg[v2*CAP2 + r] = (unsigned short)j;
    }
  }
  // init val stamps to 0xFFFF (overwrites counter alias; incl dummy+trash 1024..1091)
  { const uint4 z = make_uint4(0xFFFF0000u,0xFFFF0000u,0xFFFF0000u,0xFFFF0000u);
    uint4* p = reinterpret_cast<uint4*>(R.val);
    #pragma unroll
    for (int m = 0; m < 4; m++) p[m*64 + lane] = z;
    if (lane < 17u) p[256 + lane] = z; }                  // words 1024..1091

  // tokens -> registers
  unsigned int vtokk[16];
  #pragma unroll
  for (int k = 0; k < 16; k++) vtokk[k] = R.t[k*64 + lane];

  unsigned int lp1 = 0xFFFFFFFFu;               // lane v: last j with x[j]==v (-1 none)
  const bool lane24 = (lane < (unsigned)CAP2);
  const bool realw  = ((lane & 7u) == 7u) && (lane < 24u);  // lanes 7/15/23 -> cols 0..2
  const bool keyw   = (lane == 62u);                        // run-1 key -> col 3
  unsigned int* const wbase = realw ? &R.M8[lane >> 3] : (keyw ? &R.M8[3] : &R.trash[lane]);
  const unsigned int wsw = (realw || keyw) ? 5u : 0u;       // word stride per step
  const unsigned int trashw = 1025u + lane;

  int s_xi  = __builtin_amdgcn_readlane((int)vtokk[0], 0);
  int s_xp1 = __builtin_amdgcn_readlane((int)vtokk[0], 1);
  int s_xm1 = 0;
  unsigned int enA, enB;
  enA = (unsigned int)R.bg[((((unsigned)s_xm1 << 4) | (unsigned)s_xi ) * CAP2) + lane];
  enB = (unsigned int)R.bg[((((unsigned)s_xi  << 4) | (unsigned)s_xp1) * CAP2) + lane];

#define RSTEP(I_, NEXTTOK_EXPR) do {                                              \
    const int i_ = (I_);                                                          \
    const unsigned int jl = lane24 ? enA : SENT_J;                                \
    const int s_xp2 = (NEXTTOK_EXPR);                                             \
    const unsigned int s_bn = (((unsigned)s_xp1 << 4) | (unsigned)s_xp2);         \
    const unsigned int enN = (unsigned int)R.bg[s_bn * CAP2 + lane];              \
    const unsigned int g = R.val[jl - 1u];                                        \
    const int s_lp1 = __builtin_amdgcn_readlane((int)lp1, s_xi);                  \
    const unsigned int s_key = (s_lp1 < 0) ? 0u : (1024u + (unsigned)s_lp1);      \
    lp1 = (lane == (unsigned)s_xi) ? (unsigned)i_ : lp1;                          \
    const unsigned int d = g - (((unsigned)(i_ - 1)) << 16);                      \
    const unsigned int rn = (d <= 1024u) ? (d + 1u) : 2u;                         \
    const unsigned int widx = (jl <= 1023u) ? jl : trashw;                        \
    R.val[widx] = (((unsigned)i_) << 16) | rn;                                    \
    unsigned int key = (rn << 10) | jl;                                           \
    key = (jl < (unsigned)i_) ? key : 0u;                                         \
    int bb = (int)key, tt;                                                        \
    tt = __builtin_amdgcn_mov_dpp(bb, 0x111, 0xf, 0xf, true); bb = ((unsigned)tt > (unsigned)bb) ? tt : bb; \
    tt = __builtin_amdgcn_mov_dpp(bb, 0x112, 0xf, 0xf, true); bb = ((unsigned)tt > (unsigned)bb) ? tt : bb; \
    tt = __builtin_amdgcn_mov_dpp(bb, 0x114, 0xf, 0xf, true); bb = ((unsigned)tt > (unsigned)bb) ? tt : bb; \
    const unsigned int wval = keyw ? s_key : (unsigned)bb;                        \
    wbase[wsw * (unsigned)(i_ & 63)] = wval;                                      \
    enA = enB; enB = enN;                                                         \
    s_xm1 = s_xi; s_xi = s_xp1; s_xp1 = s_xp2;                                    \
  } while(0)

  #pragma unroll
  for (int i0 = 0; i0 < 16; i0++){
    #pragma unroll 1
    for (int di = 0; di < 62; di++){
      RSTEP(i0*64 + di, __builtin_amdgcn_readlane((int)vtokk[i0], di + 2));
    }
    RSTEP(i0*64 + 62, __builtin_amdgcn_readlane((int)vtokk[(i0+1) & 15], (i0 < 15) ? 0 : 62));
    RSTEP(i0*64 + 63, __builtin_amdgcn_readlane((int)vtokk[(i0+1) & 15], (i0 < 15) ? 1 : 63));
    // block epilogue: lane s reduces M8[s][0..3] -> pred for step i0*64+s
    const unsigned int b5 = lane * 5u;
    unsigned int ab = R.M8[b5];
    { const unsigned int v1 = R.M8[b5 + 1u]; ab = v1 > ab ? v1 : ab; }
    { const unsigned int v2 = R.M8[b5 + 2u]; ab = v2 > ab ? v2 : ab; }
    { const unsigned int v3 = R.M8[b5 + 3u]; ab = v3 > ab ? v3 : ab; }
    unsigned int pidx = (ab & 1023u) + 1u;
    pidx = pidx > 1023u ? 1023u : pidx;
    const unsigned int pt = R.t[pidx];
    pred[(size_t)row*T_ + i0*64 + lane] = (unsigned char)((ab >= 1024u) ? pt : 0u);
  }
#undef RSTEP
}

// ---------------- expand: pred (B*Cg, T) u8 -> out (B,T,C) f32 ----------------
__global__ __launch_bounds__(256) void expand_kernel(const unsigned char* __restrict__ pred,
                                                     const float* __restrict__ emb0,
                                                     const float* __restrict__ emb1,
                                                     float* __restrict__ out){
  __shared__ unsigned char pl[64][80];
  const int bid = blockIdx.x;
  const int g0 = (bid & 3) << 6;
  const int t0 = ((bid >> 2) & 15) << 6;
  const int b  = bid >> 6;
  const int k  = threadIdx.x;
  {
    const int gg = k >> 2, off = (k & 3) * 16;
    const uint4 v = *reinterpret_cast<const uint4*>(pred + (size_t)(b*CG_ + g0 + gg)*T_ + t0 + off);
    *reinterpret_cast<uint4*>(&pl[gg][off]) = v;
  }
  __syncthreads();
  const int gg = k & 63;
  const int w  = k >> 6;
  const float4 e0 = *reinterpret_cast<const float4*>(emb0 + (g0+gg)*4);
  const float4 e1 = *reinterpret_cast<const float4*>(emb1 + (g0+gg)*4);
  for (int it = 0; it < 16; it++){
    const int tt = it*4 + w;
    const unsigned int pb = pl[gg][tt];
    float4 o;
    o.x = (pb & 1u) ? e1.x : e0.x;
    o.y = (pb & 2u) ? e1.y : e0.y;
    o.z = (pb & 4u) ? e1.z : e0.z;
    o.w = (pb & 8u) ? e1.w : e0.w;
    *reinterpret_cast<float4*>(out + (size_t)(b*T_ + t0 + tt)*1024 + (g0+gg)*4) = o;
  }
}

extern "C" void kernel_launch(void* const* d_in, const int* in_sizes, int n_in,
                              void* d_out, int out_size, void* d_ws, size_t ws_size,
                              hipStream_t stream){
  const float* x    = (const float*)d_in[0];
  const float* emb0 = (const float*)d_in[1];
  const float* emb1 = (const float*)d_in[2];
  float* out = (float*)d_out;
  unsigned char* tok  = (unsigned char*)d_ws;
  unsigned char* pred = tok + (size_t)B_*CG_*T_;
  pack_kernel<<<128, 256, 0, stream>>>(x, tok);
  rosa_bg2_kernel<<<(B_*CG_)/4, 256, 0, stream>>>(tok, pred);
  expand_kernel<<<512, 256, 0, stream>>>(pred, emb0, emb1, out);
}

// Round 13
// 174.069 us; speedup vs baseline: 1.4601x; 1.2105x over previous
//
#include <hip/hip_runtime.h>

#define B_ 8
#define T_ 1024
#define CG_ 256
#define CAP2 24
#define SENT_J 1025u

// ---------------- pack: x (8,1024,1024) f32 -> tok rows (B*Cg, T) u8 ----------------
__global__ __launch_bounds__(256) void pack_kernel(const float* __restrict__ x,
                                                   unsigned char* __restrict__ tok){
  __shared__ unsigned char tl[256][80];
  const int b  = blockIdx.x >> 4;
  const int t0 = (blockIdx.x & 15) << 6;
  const int g  = threadIdx.x;
  const float* xb = x + ((size_t)(b*T_ + t0) * 1024) + g*4;
  for (int tt = 0; tt < 64; tt++){
    const float4 v = *reinterpret_cast<const float4*>(xb + (size_t)tt*1024);
    unsigned int t = (v.x>0.f?1u:0u) | (v.y>0.f?2u:0u) | (v.z>0.f?4u:0u) | (v.w>0.f?8u:0u);
    tl[g][tt] = (unsigned char)t;
  }
  __syncthreads();
  const int gg  = threadIdx.x >> 2;
  const int off = (threadIdx.x & 3) * 16;
  for (int it = 0; it < 4; it++){
    const int g2 = gg + it*64;
    const uint4 w = *reinterpret_cast<const uint4*>(&tl[g2][off]);
    *reinterpret_cast<uint4*>(tok + (size_t)(b*CG_ + g2)*T_ + t0 + off) = w;
  }
}

// Bigram-sparse ROSA DP, software-pipelined gather (1 step ahead).
//   Step i body: rn <- gA (gather issued at step i-1); write val[jl(i)];
//   ISSUE gather for step i+1 (safe: same-wave DS ops are in-order, so it sees
//   write(i) but not write(i+1)); bucket prefetch 2 ahead; run-1 via lastpos reg;
//   deferred argmax via 3-DPP group maxes -> M8 rows, reduced once per 64 steps.
//   Sentinel lanes write val[1025] (same-address collapse).
struct alignas(16) RowLds {
  unsigned int   val[1028];     // cells 0..1023; [1024] dummy-read; [1025] trash-write
                                // build alias: val[0..255] = bucket counters
  unsigned char  t[1040];       // tokens + pad
  unsigned short bg[256*CAP2];  // buckets: plain j, sentinel 1025       (12288 B)
  unsigned int   M8[320];       // [64][5]: cols 0..2 group maxes, col 3 run-1 key
  unsigned int   trash[64];
};                              // 18976 B/wave, x4 = 75904 B -> 2 blocks/CU

__global__ __launch_bounds__(256, 2) void rosa_bg3_kernel(const unsigned char* __restrict__ tok,
                                                          unsigned char* __restrict__ pred){
  __shared__ RowLds S[4];
  const int wave = threadIdx.x >> 6;
  const unsigned int lane = threadIdx.x & 63u;
  const int row = blockIdx.x * 4 + wave;
  RowLds& R = S[wave];

  // stage tokens + pad
  { const uint4 v = *reinterpret_cast<const uint4*>(tok + (size_t)row*T_ + lane*16);
    *reinterpret_cast<uint4*>(&R.t[lane*16]) = v;
    if (lane == 0u) *reinterpret_cast<uint4*>(&R.t[1024]) = make_uint4(0,0,0,0); }
  // zero bucket counters (aliased over val[0..255])
  { uint4* p = reinterpret_cast<uint4*>(R.val);
    p[lane] = make_uint4(0,0,0,0); }
  // fill bg with sentinel
  { const unsigned int s2 = SENT_J | (SENT_J << 16);
    const uint4 s4 = make_uint4(s2,s2,s2,s2);
    uint4* p = reinterpret_cast<uint4*>(R.bg);
    #pragma unroll
    for (int m = 0; m < 12; m++) p[m*64 + lane] = s4; }
  // build buckets (order within bucket irrelevant; same-wave DS ordering)
  #pragma unroll
  for (int k = 0; k < 16; k++){
    const unsigned int j = (unsigned)k*64u + lane;
    if (j >= 1u){
      const unsigned int v2 = ((unsigned)R.t[j-1] << 4) | (unsigned)R.t[j];
      const unsigned int r = atomicAdd(&R.val[v2], 1u);
      if (r < (unsigned)CAP2) R.bg[v2*CAP2 + r] = (unsigned short)j;
    }
  }
  // init val stamps to 0xFFFF (overwrites counter alias; incl slots 1024..1027)
  { const uint4 z = make_uint4(0xFFFF0000u,0xFFFF0000u,0xFFFF0000u,0xFFFF0000u);
    uint4* p = reinterpret_cast<uint4*>(R.val);
    #pragma unroll
    for (int m = 0; m < 4; m++) p[m*64 + lane] = z;
    if (lane == 0u) p[256] = z; }

  // tokens -> registers
  unsigned int vtokk[16];
  #pragma unroll
  for (int k = 0; k < 16; k++) vtokk[k] = R.t[k*64 + lane];

  unsigned int lp1 = 0xFFFFFFFFu;               // lane v: last j with x[j]==v (-1 none)
  const bool lane24 = (lane < (unsigned)CAP2);
  const bool realw  = ((lane & 7u) == 7u) && (lane < 24u);  // lanes 7/15/23 -> cols 0..2
  const bool keyw   = (lane == 62u);                        // run-1 key -> col 3
  unsigned int* const wbase = realw ? &R.M8[lane >> 3] : (keyw ? &R.M8[3] : &R.trash[lane]);
  const unsigned int wsw = (realw || keyw) ? 5u : 0u;       // word stride per step

  int s_xi  = __builtin_amdgcn_readlane((int)vtokk[0], 0);
  int s_xp1 = __builtin_amdgcn_readlane((int)vtokk[0], 1);
  // prologue: buckets for steps 0 and 1, prime gather for step 0
  unsigned int enA = (unsigned int)R.bg[(((0u << 4) | (unsigned)s_xi ) * CAP2) + lane];
  unsigned int enB = (unsigned int)R.bg[((((unsigned)s_xi << 4) | (unsigned)s_xp1) * CAP2) + lane];
  unsigned int gA;
  { const unsigned int jl0 = lane24 ? enA : SENT_J;
    gA = R.val[jl0 - 1u]; }

#define RSTEP(I_, NEXTTOK_EXPR) do {                                              \
    const int i_ = (I_);                                                          \
    const unsigned int jlA = lane24 ? enA : SENT_J;                               \
    const int s_xp2 = (NEXTTOK_EXPR);                                             \
    const unsigned int s_bn = (((unsigned)s_xp1 << 4) | (unsigned)s_xp2);         \
    const unsigned int enN = (unsigned int)R.bg[s_bn * CAP2 + lane];              \
    /* rn from the 1-step-early gather */                                         \
    const unsigned int d = gA - (((unsigned)(i_ - 1)) << 16);                     \
    const unsigned int rn = (d <= 1024u) ? (d + 1u) : 2u;                         \
    R.val[jlA] = (((unsigned)i_) << 16) | rn;   /* sentinels collapse on 1025 */  \
    /* issue gather for step i+1 (after write(i): same-wave DS in-order) */       \
    const unsigned int jlB = lane24 ? enB : SENT_J;                               \
    const unsigned int gB = R.val[jlB - 1u];                                      \
    /* run-1 scalar key */                                                        \
    const int s_lp1 = __builtin_amdgcn_readlane((int)lp1, s_xi);                  \
    const unsigned int s_key = (s_lp1 < 0) ? 0u : (1024u + (unsigned)s_lp1);      \
    lp1 = (lane == (unsigned)s_xi) ? (unsigned)i_ : lp1;                          \
    unsigned int key = (rn << 10) | jlA;                                          \
    key = (jlA < (unsigned)i_) ? key : 0u;                                        \
    int bb = (int)key, tt;                                                        \
    tt = __builtin_amdgcn_mov_dpp(bb, 0x111, 0xf, 0xf, true); bb = ((unsigned)tt > (unsigned)bb) ? tt : bb; \
    tt = __builtin_amdgcn_mov_dpp(bb, 0x112, 0xf, 0xf, true); bb = ((unsigned)tt > (unsigned)bb) ? tt : bb; \
    tt = __builtin_amdgcn_mov_dpp(bb, 0x114, 0xf, 0xf, true); bb = ((unsigned)tt > (unsigned)bb) ? tt : bb; \
    const unsigned int wval = keyw ? s_key : (unsigned)bb;                        \
    wbase[wsw * (unsigned)(i_ & 63)] = wval;                                      \
    enA = enB; enB = enN; gA = gB;                                                \
    s_xi = s_xp1; s_xp1 = s_xp2;                                                  \
  } while(0)

  #pragma unroll
  for (int i0 = 0; i0 < 16; i0++){
    #pragma unroll 2
    for (int di = 0; di < 62; di++){
      RSTEP(i0*64 + di, __builtin_amdgcn_readlane((int)vtokk[i0], di + 2));
    }
    RSTEP(i0*64 + 62, __builtin_amdgcn_readlane((int)vtokk[(i0+1) & 15], (i0 < 15) ? 0 : 62));
    RSTEP(i0*64 + 63, __builtin_amdgcn_readlane((int)vtokk[(i0+1) & 15], (i0 < 15) ? 1 : 63));
    // block epilogue: lane s reduces M8[s][0..3] -> pred for step i0*64+s
    const unsigned int b5 = lane * 5u;
    unsigned int ab = R.M8[b5];
    { const unsigned int v1 = R.M8[b5 + 1u]; ab = v1 > ab ? v1 : ab; }
    { const unsigned int v2 = R.M8[b5 + 2u]; ab = v2 > ab ? v2 : ab; }
    { const unsigned int v3 = R.M8[b5 + 3u]; ab = v3 > ab ? v3 : ab; }
    unsigned int pidx = (ab & 1023u) + 1u;
    pidx = pidx > 1023u ? 1023u : pidx;
    const unsigned int pt = R.t[pidx];
    pred[(size_t)row*T_ + i0*64 + lane] = (unsigned char)((ab >= 1024u) ? pt : 0u);
  }
#undef RSTEP
}

// ---------------- expand: pred (B*Cg, T) u8 -> out (B,T,C) f32 ----------------
__global__ __launch_bounds__(256) void expand_kernel(const unsigned char* __restrict__ pred,
                                                     const float* __restrict__ emb0,
                                                     const float* __restrict__ emb1,
                                                     float* __restrict__ out){
  __shared__ unsigned char pl[64][80];
  const int bid = blockIdx.x;
  const int g0 = (bid & 3) << 6;
  const int t0 = ((bid >> 2) & 15) << 6;
  const int b  = bid >> 6;
  const int k  = threadIdx.x;
  {
    const int gg = k >> 2, off = (k & 3) * 16;
    const uint4 v = *reinterpret_cast<const uint4*>(pred + (size_t)(b*CG_ + g0 + gg)*T_ + t0 + off);
    *reinterpret_cast<uint4*>(&pl[gg][off]) = v;
  }
  __syncthreads();
  const int gg = k & 63;
  const int w  = k >> 6;
  const float4 e0 = *reinterpret_cast<const float4*>(emb0 + (g0+gg)*4);
  const float4 e1 = *reinterpret_cast<const float4*>(emb1 + (g0+gg)*4);
  for (int it = 0; it < 16; it++){
    const int tt = it*4 + w;
    const unsigned int pb = pl[gg][tt];
    float4 o;
    o.x = (pb & 1u) ? e1.x : e0.x;
    o.y = (pb & 2u) ? e1.y : e0.y;
    o.z = (pb & 4u) ? e1.z : e0.z;
    o.w = (pb & 8u) ? e1.w : e0.w;
    *reinterpret_cast<float4*>(out + (size_t)(b*T_ + t0 + tt)*1024 + (g0+gg)*4) = o;
  }
}

extern "C" void kernel_launch(void* const* d_in, const int* in_sizes, int n_in,
                              void* d_out, int out_size, void* d_ws, size_t ws_size,
                              hipStream_t stream){
  const float* x    = (const float*)d_in[0];
  const float* emb0 = (const float*)d_in[1];
  const float* emb1 = (const float*)d_in[2];
  float* out = (float*)d_out;
  unsigned char* tok  = (unsigned char*)d_ws;
  unsigned char* pred = tok + (size_t)B_*CG_*T_;
  pack_kernel<<<128, 256, 0, stream>>>(x, tok);
  rosa_bg3_kernel<<<(B_*CG_)/4, 256, 0, stream>>>(tok, pred);
  expand_kernel<<<512, 256, 0, stream>>>(pred, emb0, emb1, out);
}

// Round 14
// 159.127 us; speedup vs baseline: 1.5972x; 1.0939x over previous
//
#include <hip/hip_runtime.h>

#define B_ 8
#define T_ 1024
#define CG_ 256
#define CAP2 24
#define SENT_J 1025u

// ---------------- pack: x (8,1024,1024) f32 -> tok rows (B*Cg, T) u8 ----------------
__global__ __launch_bounds__(256) void pack_kernel(const float* __restrict__ x,
                                                   unsigned char* __restrict__ tok){
  __shared__ unsigned char tl[256][80];
  const int b  = blockIdx.x >> 4;
  const int t0 = (blockIdx.x & 15) << 6;
  const int g  = threadIdx.x;
  const float* xb = x + ((size_t)(b*T_ + t0) * 1024) + g*4;
  for (int tt = 0; tt < 64; tt++){
    const float4 v = *reinterpret_cast<const float4*>(xb + (size_t)tt*1024);
    unsigned int t = (v.x>0.f?1u:0u) | (v.y>0.f?2u:0u) | (v.z>0.f?4u:0u) | (v.w>0.f?8u:0u);
    tl[g][tt] = (unsigned char)t;
  }
  __syncthreads();
  const int gg  = threadIdx.x >> 2;
  const int off = (threadIdx.x & 3) * 16;
  for (int it = 0; it < 4; it++){
    const int g2 = gg + it*64;
    const uint4 w = *reinterpret_cast<const uint4*>(&tl[g2][off]);
    *reinterpret_cast<uint4*>(tok + (size_t)(b*CG_ + g2)*T_ + t0 + off) = w;
  }
}

// Bigram-sparse ROSA DP, pipelined gather + precomputed run-1 keys (prevocc).
//   step i: rn from gather issued at i-1 (fresh stamp i-1 -> run+1, stale -> 2);
//   write val[jl]; issue gather(i+1); 3-DPP group maxes -> M8[di][0..2];
//   run-1 key = 1024+prevocc[i], precomputed into pvk[] VGPRs at build,
//   folded in at the block epilogue (lane s handles step s).
struct alignas(16) RowLds {
  unsigned int   val[1028];     // cells 0..1023; [1024] dummy-read; [1025] trash-write
                                // build alias: val[0..255] = bucket counters
  unsigned char  t[1040];       // tokens + pad
  unsigned short bg[256*CAP2];  // buckets: plain j, sentinel 1025       (12288 B)
  unsigned int   M8[320];       // [64][5]: cols 0..2 = 8-lane-group maxes
  unsigned int   trash[64];
};                              // 18976 B/wave, x4 = 75904 B -> 2 blocks/CU

__global__ __launch_bounds__(256, 2) void rosa_bg4_kernel(const unsigned char* __restrict__ tok,
                                                          unsigned char* __restrict__ pred){
  __shared__ RowLds S[4];
  const int wave = threadIdx.x >> 6;
  const unsigned int lane = threadIdx.x & 63u;
  const int row = blockIdx.x * 4 + wave;
  RowLds& R = S[wave];

  // stage tokens + pad
  { const uint4 v = *reinterpret_cast<const uint4*>(tok + (size_t)row*T_ + lane*16);
    *reinterpret_cast<uint4*>(&R.t[lane*16]) = v;
    if (lane == 0u) *reinterpret_cast<uint4*>(&R.t[1024]) = make_uint4(0,0,0,0); }
  // zero bucket counters (aliased over val[0..255])
  { uint4* p = reinterpret_cast<uint4*>(R.val);
    p[lane] = make_uint4(0,0,0,0); }
  // fill bg with sentinel
  { const unsigned int s2 = SENT_J | (SENT_J << 16);
    const uint4 s4 = make_uint4(s2,s2,s2,s2);
    uint4* p = reinterpret_cast<uint4*>(R.bg);
    #pragma unroll
    for (int m = 0; m < 12; m++) p[m*64 + lane] = s4; }

  // tokens -> registers (after staging; same-wave DS in-order)
  unsigned int vtokk[16];
  #pragma unroll
  for (int k = 0; k < 16; k++) vtokk[k] = R.t[k*64 + lane];

  // build buckets (order within bucket irrelevant)
  #pragma unroll
  for (int k = 0; k < 16; k++){
    const unsigned int j = (unsigned)k*64u + lane;
    if (j >= 1u){
      const unsigned int v2 = ((unsigned)R.t[j-1] << 4) | (unsigned)R.t[j];
      const unsigned int r = atomicAdd(&R.val[v2], 1u);
      if (r < (unsigned)CAP2) R.bg[v2*CAP2 + r] = (unsigned short)j;
    }
  }

  // ---- build prevocc keys: pvk[c] lane l = run-1 key for step c*64+l ----
  // key = 0 if no j<i with x[j]==x[i], else 1024 + (largest such j)
  const unsigned long long below = (1ull << lane) - 1ull;
  unsigned int pvk[16];
  int lp1c = -1;                    // lane v (v<16): last pos so far with token v
  #pragma unroll 1
  for (int c = 0; c < 16; c++){
    const unsigned int tj = vtokk[c];
    const unsigned long long b0 = __ballot((tj & 1u) != 0u);
    const unsigned long long b1 = __ballot((tj & 2u) != 0u);
    const unsigned long long b2 = __ballot((tj & 4u) != 0u);
    const unsigned long long b3 = __ballot((tj & 8u) != 0u);
    unsigned long long mm = ((tj & 1u) ? b0 : ~b0) & ((tj & 2u) ? b1 : ~b1)
                          & ((tj & 4u) ? b2 : ~b2) & ((tj & 8u) ? b3 : ~b3);
    const unsigned long long mlo = mm & below;
    const int pin = 63 - __builtin_clzll(mlo | 1ull);     // valid iff mlo!=0
    const int pg  = __builtin_amdgcn_ds_bpermute((int)(tj << 2), lp1c);
    const int pv  = mlo ? (c*64 + pin) : pg;
    pvk[c] = (pv < 0) ? 0u : (1024u + (unsigned)pv);
    // update carry: lane-as-value mask
    unsigned long long mv = ((lane & 1u) ? b0 : ~b0) & ((lane & 2u) ? b1 : ~b1)
                          & ((lane & 4u) ? b2 : ~b2) & ((lane & 8u) ? b3 : ~b3);
    if (mv) lp1c = c*64 + 63 - __builtin_clzll(mv);
  }

  // init val stamps to 0xFFFF (overwrites counter alias; incl slots 1024..1027)
  { const uint4 z = make_uint4(0xFFFF0000u,0xFFFF0000u,0xFFFF0000u,0xFFFF0000u);
    uint4* p = reinterpret_cast<uint4*>(R.val);
    #pragma unroll
    for (int m = 0; m < 4; m++) p[m*64 + lane] = z;
    if (lane == 0u) p[256] = z; }

  const bool lane24 = (lane < (unsigned)CAP2);
  const bool realw  = ((lane & 7u) == 7u) && (lane < 24u);  // lanes 7/15/23 -> cols 0..2
  unsigned int* const wbase0 = realw ? &R.M8[lane >> 3] : &R.trash[lane];
  const unsigned int wstep = realw ? 5u : 0u;               // words per step

  // prologue: buckets for steps 0,1 and primed gather for step 0
  const unsigned int x0 = (unsigned)__builtin_amdgcn_readlane((int)vtokk[0], 0);
  const unsigned int x1 = (unsigned)__builtin_amdgcn_readlane((int)vtokk[0], 1);
  unsigned int enA = (unsigned int)R.bg[x0 * CAP2 + lane];                  // (0<<4)|x0
  unsigned int enB = (unsigned int)R.bg[((x0 << 4) | x1) * CAP2 + lane];
  unsigned int gA;
  { const unsigned int jl0 = lane24 ? enA : SENT_J;
    gA = R.val[jl0 - 1u]; }
  int s_xp1 = (int)x1;                      // x[i+1]

#define RSTEP(I_, NEXTTOK_EXPR) do {                                              \
    const int i_ = (I_);                                                          \
    const unsigned int jlA = lane24 ? enA : SENT_J;                               \
    const int s_xp2 = (NEXTTOK_EXPR);                                             \
    const unsigned int s_bn = (((unsigned)s_xp1 << 4) | (unsigned)s_xp2);         \
    const unsigned int enN = (unsigned int)R.bg[s_bn * CAP2 + lane];              \
    const unsigned int d = gA - (((unsigned)(i_ - 1)) << 16);                     \
    const unsigned int rn = (d <= 1024u) ? (d + 1u) : 2u;                         \
    R.val[jlA] = (((unsigned)i_) << 16) | rn;                                     \
    const unsigned int jlB = lane24 ? enB : SENT_J;                               \
    const unsigned int gB = R.val[jlB - 1u];                                      \
    unsigned int key = (rn << 10) | jlA;                                          \
    key = (jlA < (unsigned)i_) ? key : 0u;                                        \
    int bb = (int)key, tt;                                                        \
    tt = __builtin_amdgcn_mov_dpp(bb, 0x111, 0xf, 0xf, true); bb = ((unsigned)tt > (unsigned)bb) ? tt : bb; \
    tt = __builtin_amdgcn_mov_dpp(bb, 0x112, 0xf, 0xf, true); bb = ((unsigned)tt > (unsigned)bb) ? tt : bb; \
    tt = __builtin_amdgcn_mov_dpp(bb, 0x114, 0xf, 0xf, true); bb = ((unsigned)tt > (unsigned)bb) ? tt : bb; \
    *wptr = (unsigned)bb;                                                         \
    wptr += wstep;                                                                \
    enA = enB; enB = enN; gA = gB;                                                \
    s_xp1 = s_xp2;                                                                \
  } while(0)

  #pragma unroll
  for (int i0 = 0; i0 < 16; i0++){
    unsigned int* wptr = wbase0;
    #pragma unroll 2
    for (int di = 0; di < 62; di++){
      RSTEP(i0*64 + di, __builtin_amdgcn_readlane((int)vtokk[i0], di + 2));
    }
    RSTEP(i0*64 + 62, __builtin_amdgcn_readlane((int)vtokk[(i0+1) & 15], (i0 < 15) ? 0 : 62));
    RSTEP(i0*64 + 63, __builtin_amdgcn_readlane((int)vtokk[(i0+1) & 15], (i0 < 15) ? 1 : 63));
    // block epilogue: lane s reduces M8[s][0..2] + precomputed run-1 key
    const unsigned int b5 = lane * 5u;
    unsigned int ab = R.M8[b5];
    { const unsigned int v1 = R.M8[b5 + 1u]; ab = v1 > ab ? v1 : ab; }
    { const unsigned int v2 = R.M8[b5 + 2u]; ab = v2 > ab ? v2 : ab; }
    { const unsigned int v3 = pvk[i0];       ab = v3 > ab ? v3 : ab; }
    unsigned int pidx = (ab & 1023u) + 1u;
    pidx = pidx > 1023u ? 1023u : pidx;
    const unsigned int pt = R.t[pidx];
    pred[(size_t)row*T_ + i0*64 + lane] = (unsigned char)((ab >= 1024u) ? pt : 0u);
  }
#undef RSTEP
}

// ---------------- expand: pred (B*Cg, T) u8 -> out (B,T,C) f32 ----------------
__global__ __launch_bounds__(256) void expand_kernel(const unsigned char* __restrict__ pred,
                                                     const float* __restrict__ emb0,
                                                     const float* __restrict__ emb1,
                                                     float* __restrict__ out){
  __shared__ unsigned char pl[64][80];
  const int bid = blockIdx.x;
  const int g0 = (bid & 3) << 6;
  const int t0 = ((bid >> 2) & 15) << 6;
  const int b  = bid >> 6;
  const int k  = threadIdx.x;
  {
    const int gg = k >> 2, off = (k & 3) * 16;
    const uint4 v = *reinterpret_cast<const uint4*>(pred + (size_t)(b*CG_ + g0 + gg)*T_ + t0 + off);
    *reinterpret_cast<uint4*>(&pl[gg][off]) = v;
  }
  __syncthreads();
  const int gg = k & 63;
  const int w  = k >> 6;
  const float4 e0 = *reinterpret_cast<const float4*>(emb0 + (g0+gg)*4);
  const float4 e1 = *reinterpret_cast<const float4*>(emb1 + (g0+gg)*4);
  for (int it = 0; it < 16; it++){
    const int tt = it*4 + w;
    const unsigned int pb = pl[gg][tt];
    float4 o;
    o.x = (pb & 1u) ? e1.x : e0.x;
    o.y = (pb & 2u) ? e1.y : e0.y;
    o.z = (pb & 4u) ? e1.z : e0.z;
    o.w = (pb & 8u) ? e1.w : e0.w;
    *reinterpret_cast<float4*>(out + (size_t)(b*T_ + t0 + tt)*1024 + (g0+gg)*4) = o;
  }
}

extern "C" void kernel_launch(void* const* d_in, const int* in_sizes, int n_in,
                              void* d_out, int out_size, void* d_ws, size_t ws_size,
                              hipStream_t stream){
  const float* x    = (const float*)d_in[0];
  const float* emb0 = (const float*)d_in[1];
  const float* emb1 = (const float*)d_in[2];
  float* out = (float*)d_out;
  unsigned char* tok  = (unsigned char*)d_ws;
  unsigned char* pred = tok + (size_t)B_*CG_*T_;
  pack_kernel<<<128, 256, 0, stream>>>(x, tok);
  rosa_bg4_kernel<<<(B_*CG_)/4, 256, 0, stream>>>(tok, pred);
  expand_kernel<<<512, 256, 0, stream>>>(pred, emb0, emb1, out);
}